// Round 1
// baseline (494.737 us; speedup 1.0000x reference)
//
#include <hip/hip_runtime.h>
#include <hip/hip_bf16.h>
#include <math.h>

typedef __attribute__((ext_vector_type(8))) short short8;
typedef __attribute__((ext_vector_type(4))) float floatx4;

__device__ inline unsigned f2bf1(float f) {
    union { float f; unsigned u; } v; v.f = f;
    return (v.u + 0x8000u) >> 16;   // round-half-up to bf16
}

__device__ inline short8 pack8(float4 a, float4 b) {
    short8 r;
    r[0] = (short)f2bf1(a.x); r[1] = (short)f2bf1(a.y);
    r[2] = (short)f2bf1(a.z); r[3] = (short)f2bf1(a.w);
    r[4] = (short)f2bf1(b.x); r[5] = (short)f2bf1(b.y);
    r[6] = (short)f2bf1(b.z); r[7] = (short)f2bf1(b.w);
    return r;
}

// -------- segment-average: x (16,128,512) -> xcf (32, 2048), m = b*16 + a ----
__global__ __launch_bounds__(128) void avg_k(const float* __restrict__ x,
                                             float* __restrict__ xcf) {
    int blk = blockIdx.x;            // a*128 + b
    int a = blk >> 7, b = blk & 127;
    int t = threadIdx.x;
    const float4 v = *(const float4*)(x + ((size_t)a * 128 + b) * 512 + t * 4);
    float s = v.x + v.y + v.z + v.w;
    s += __shfl_xor(s, 1);
    s += __shfl_xor(s, 2);
    if ((t & 3) == 0) {
        int seg = t >> 2;            // 0..31
        xcf[seg * 2048 + b * 16 + a] = s * (1.0f / 16.0f);
    }
}

// -------- LayerNorm over rows of 2048; addres: out = LN(x)+x (in-place ok) ---
__global__ __launch_bounds__(256) void ln_k(const float* __restrict__ Sin,
                                            const float* __restrict__ g,
                                            const float* __restrict__ b,
                                            float* __restrict__ out, int addres) {
    __shared__ float red[8];
    const int row = blockIdx.x, t = threadIdx.x;
    const float* xr = Sin + (size_t)row * 2048;
    float4 v0 = *(const float4*)(xr + t * 4);
    float4 v1 = *(const float4*)(xr + 1024 + t * 4);
    float s = v0.x + v0.y + v0.z + v0.w + v1.x + v1.y + v1.z + v1.w;
    for (int o = 32; o; o >>= 1) s += __shfl_down(s, o);
    if ((t & 63) == 0) red[t >> 6] = s;
    __syncthreads();
    float mean = (red[0] + red[1] + red[2] + red[3]) * (1.0f / 2048.0f);
    float d0 = v0.x - mean, d1 = v0.y - mean, d2 = v0.z - mean, d3 = v0.w - mean;
    float e0 = v1.x - mean, e1 = v1.y - mean, e2 = v1.z - mean, e3 = v1.w - mean;
    float s2 = d0*d0 + d1*d1 + d2*d2 + d3*d3 + e0*e0 + e1*e1 + e2*e2 + e3*e3;
    for (int o = 32; o; o >>= 1) s2 += __shfl_down(s2, o);
    if ((t & 63) == 0) red[4 + (t >> 6)] = s2;
    __syncthreads();
    float var = (red[4] + red[5] + red[6] + red[7]) * (1.0f / 2048.0f);
    float rs = 1.0f / sqrtf(var + 1e-5f);
    float4 g0 = *(const float4*)(g + t * 4);
    float4 g1 = *(const float4*)(g + 1024 + t * 4);
    float4 b0 = *(const float4*)(b + t * 4);
    float4 b1 = *(const float4*)(b + 1024 + t * 4);
    float4 o0, o1;
    o0.x = d0 * rs * g0.x + b0.x; o0.y = d1 * rs * g0.y + b0.y;
    o0.z = d2 * rs * g0.z + b0.z; o0.w = d3 * rs * g0.w + b0.w;
    o1.x = e0 * rs * g1.x + b1.x; o1.y = e1 * rs * g1.y + b1.y;
    o1.z = e2 * rs * g1.z + b1.z; o1.w = e3 * rs * g1.w + b1.w;
    if (addres) {
        o0.x += v0.x; o0.y += v0.y; o0.z += v0.z; o0.w += v0.w;
        o1.x += v1.x; o1.y += v1.y; o1.z += v1.z; o1.w += v1.w;
    }
    *(float4*)(out + (size_t)row * 2048 + t * 4) = o0;
    *(float4*)(out + (size_t)row * 2048 + 1024 + t * 4) = o1;
}

// -------- inclusive prefix sum over i of V (32 x 2048), in place -------------
__global__ __launch_bounds__(256) void cumsum_k(float* __restrict__ V) {
    int c = blockIdx.x * 256 + threadIdx.x;
    float run = 0.f;
#pragma unroll
    for (int i = 0; i < 32; i++) { run += V[i * 2048 + c]; V[i * 2048 + c] = run; }
}

// -------- H = gelu(H + fc1_b), H is 32 x 8192 --------------------------------
__global__ __launch_bounds__(256) void gelu_k(float* __restrict__ H,
                                              const float* __restrict__ b1) {
    int idx4 = blockIdx.x * 256 + threadIdx.x;   // 65536 float4s
    int col4 = idx4 & 2047;
    float4 v = *(const float4*)(H + (size_t)idx4 * 4);
    const float4 bb = *(const float4*)(b1 + col4 * 4);
    v.x += bb.x; v.y += bb.y; v.z += bb.z; v.w += bb.w;
    v.x = 0.5f * v.x * (1.0f + erff(v.x * 0.70710678118654752f));
    v.y = 0.5f * v.y * (1.0f + erff(v.y * 0.70710678118654752f));
    v.z = 0.5f * v.z * (1.0f + erff(v.z * 0.70710678118654752f));
    v.w = 0.5f * v.w * (1.0f + erff(v.w * 0.70710678118654752f));
    *(float4*)(H + (size_t)idx4 * 4) = v;
}

// -------- thin GEMM: C[32,N] += X[32,K] @ W[N,K]^T, split-K via atomics ------
// MODE 0: plain; MODE 1: +bias[n] (on by==0); MODE 2: +sinusoidal posbias (by==0)
template<int KCHUNK, int MODE>
__global__ __launch_bounds__(256) void gemm_k(const float* __restrict__ X,
                                              const float* __restrict__ W,
                                              float* __restrict__ C,
                                              const float* __restrict__ bias,
                                              int N, int K) {
    constexpr int PITCH = KCHUNK + 8;            // +8 bf16 = 16B pad, kills bank conflicts
    __shared__ unsigned short Xs[32 * PITCH];
    const int tid = threadIdx.x;
    const int bx = blockIdx.x, by = blockIdx.y;
    const int kb0 = by * KCHUNK;

    // stage X tile fp32 -> bf16 into LDS
    constexpr int NF4 = 32 * (KCHUNK / 4);
    for (int f = tid; f < NF4; f += 256) {
        int row = f / (KCHUNK / 4), c4 = f % (KCHUNK / 4);
        const float4 v = *(const float4*)(X + (size_t)row * K + kb0 + c4 * 4);
        ushort4 p;
        p.x = (unsigned short)f2bf1(v.x);
        p.y = (unsigned short)f2bf1(v.y);
        p.z = (unsigned short)f2bf1(v.z);
        p.w = (unsigned short)f2bf1(v.w);
        *(ushort4*)&Xs[row * PITCH + c4 * 4] = p;
    }
    __syncthreads();

    const int w = tid >> 6, lane = tid & 63;
    const int q = lane >> 4, r16 = lane & 15;
    const int nb = bx * 128 + w * 32;
    floatx4 acc[2][2] = {};
    const float* wp0 = W + (size_t)(nb + r16) * K + kb0 + q * 8;
    const float* wp1 = W + (size_t)(nb + 16 + r16) * K + kb0 + q * 8;

#pragma unroll
    for (int kk = 0; kk < KCHUNK; kk += 32) {
        short8 a0 = *(const short8*)&Xs[r16 * PITCH + kk + q * 8];
        short8 a1 = *(const short8*)&Xs[(16 + r16) * PITCH + kk + q * 8];
        {
            float4 u0 = *(const float4*)(wp0 + kk);
            float4 u1 = *(const float4*)(wp0 + kk + 4);
            short8 bf = pack8(u0, u1);
            acc[0][0] = __builtin_amdgcn_mfma_f32_16x16x32_bf16(a0, bf, acc[0][0], 0, 0, 0);
            acc[1][0] = __builtin_amdgcn_mfma_f32_16x16x32_bf16(a1, bf, acc[1][0], 0, 0, 0);
        }
        {
            float4 u0 = *(const float4*)(wp1 + kk);
            float4 u1 = *(const float4*)(wp1 + kk + 4);
            short8 bf = pack8(u0, u1);
            acc[0][1] = __builtin_amdgcn_mfma_f32_16x16x32_bf16(a0, bf, acc[0][1], 0, 0, 0);
            acc[1][1] = __builtin_amdgcn_mfma_f32_16x16x32_bf16(a1, bf, acc[1][1], 0, 0, 0);
        }
    }

#pragma unroll
    for (int mt = 0; mt < 2; mt++)
#pragma unroll
        for (int nt = 0; nt < 2; nt++)
#pragma unroll
            for (int e = 0; e < 4; e++) {
                int i = mt * 16 + q * 4 + e;          // C/D: row = quad*4 + reg
                int n = nb + nt * 16 + r16;           //      col = lane&15
                float v = acc[mt][nt][e];
                if (MODE == 1 && by == 0) v += bias[n];
                if (MODE == 2 && by == 0) {
                    int ne = n & ~1;
                    float ang = (float)i * __expf(-(float)ne * (9.210340371976184f / 1024.0f));
                    v += (n & 1) ? cosf(ang) : sinf(ang);
                }
                atomicAdd(C + (size_t)i * N + n, v);
            }
}

extern "C" void kernel_launch(void* const* d_in, const int* in_sizes, int n_in,
                              void* d_out, int out_size, void* d_ws, size_t ws_size,
                              hipStream_t stream) {
    const float* x      = (const float*)d_in[0];
    const float* weight = (const float*)d_in[1];
    // d_in[2] = Wq, d_in[3] = Wk: dead (softmax over a scalar == 1)
    const float* Wv     = (const float*)d_in[4];
    const float* Wo     = (const float*)d_in[5];
    const float* ln1g   = (const float*)d_in[6];
    const float* ln1b   = (const float*)d_in[7];
    const float* ln2g   = (const float*)d_in[8];
    const float* ln2b   = (const float*)d_in[9];
    const float* fc1w   = (const float*)d_in[10];
    const float* fc1b   = (const float*)d_in[11];
    const float* fc2w   = (const float*)d_in[12];
    const float* fc2b   = (const float*)d_in[13];
    float* ws  = (float*)d_ws;
    float* xcf = ws;                 // 32*2048
    float* S   = ws + 65536;         // 32*2048
    float* Xn  = ws + 131072;        // 32*2048
    float* V   = ws + 196608;        // 32*2048
    float* H   = ws + 262144;        // 32*8192
    float* out = (float*)d_out;

    avg_k<<<2048, 128, 0, stream>>>(x, xcf);

    hipMemsetAsync(S, 0, 65536 * 4, stream);
    gemm_k<128, 2><<<dim3(16, 16), 256, 0, stream>>>(xcf, weight, S, nullptr, 2048, 2048);

    for (int a = 0; a < 3; a++) {
        ln_k<<<32, 256, 0, stream>>>(S, ln1g, ln1b, Xn, 0);
        hipMemsetAsync(V, 0, 65536 * 4, stream);
        gemm_k<128, 0><<<dim3(16, 16), 256, 0, stream>>>(Xn, Wv + (size_t)a * 4194304, V, nullptr, 2048, 2048);
        cumsum_k<<<8, 256, 0, stream>>>(V);
        gemm_k<128, 0><<<dim3(16, 16), 256, 0, stream>>>(V, Wo + (size_t)a * 4194304, S, nullptr, 2048, 2048);
        ln_k<<<32, 256, 0, stream>>>(S, ln2g, ln2b, S, 1);
        hipMemsetAsync(H, 0, 262144 * 4, stream);
        gemm_k<256, 0><<<dim3(64, 8), 256, 0, stream>>>(S, fc1w, H, nullptr, 8192, 2048);
        gelu_k<<<256, 256, 0, stream>>>(H, fc1b);
        float* Co = (a == 2) ? out : S;
        hipMemsetAsync(Co, 0, 65536 * 4, stream);
        gemm_k<256, 1><<<dim3(16, 32), 256, 0, stream>>>(H, fc2w, Co, fc2b, 2048, 8192);
    }
}